// Round 10
// baseline (292.451 us; speedup 1.0000x reference)
//
#include <hip/hip_runtime.h>
#include <stdint.h>

typedef unsigned short u16;
typedef __attribute__((ext_vector_type(8))) short bf16x8;
typedef __attribute__((ext_vector_type(4))) float f32x4;

#define MFMA(a,b,c) __builtin_amdgcn_mfma_f32_16x16x32_bf16((a),(b),(c),0,0,0)

static constexpr int S  = 4096;
static constexpr int D  = 768;
static constexpr int H  = 12;
static constexpr int HD = 64;

// float -> bf16 round-nearest-even
__device__ __forceinline__ u16 f2b(float f){
  union { float f; unsigned u; } v; v.f = f;
  unsigned r = (v.u + 0x7fffu + ((v.u >> 16) & 1u)) >> 16;
  return (u16)r;
}

// pack 2 floats -> 2 bf16 (truncation) in ONE v_perm_b32
__device__ __forceinline__ unsigned pack_bf16_trunc(float a, float b){
  return __builtin_amdgcn_perm(__float_as_uint(b), __float_as_uint(a), 0x07060302u);
}

// async global->LDS 16B per lane (DMA path, no VGPR round-trip)
__device__ __forceinline__ void cp16(const u16* g, u16* l){
  __builtin_amdgcn_global_load_lds(
      (const __attribute__((address_space(1))) unsigned int*)g,
      (__attribute__((address_space(3))) unsigned int*)l, 16, 0, 0);
}

// ---------------- fused cast fp32 -> bf16 for x + 4 weights ----------------
static constexpr int NX4 = (2 * S * D) / 4;   // 1572864
static constexpr int NW4 = (D * D) / 4;       // 147456
__global__ void castall(const float* __restrict__ x,  const float* __restrict__ wq,
                        const float* __restrict__ wk, const float* __restrict__ wv,
                        const float* __restrict__ wo,
                        u16* __restrict__ xb,  u16* __restrict__ wqb,
                        u16* __restrict__ wkb, u16* __restrict__ wvb,
                        u16* __restrict__ wob){
  int i = blockIdx.x * 256 + threadIdx.x;
  const float* s; u16* d; int off;
  if (i < NX4) { s = x; d = xb; off = i; }
  else {
    int j = i - NX4; int wsel = j / NW4; off = j - wsel * NW4;
    if (wsel >= 4) return;
    s = (wsel == 0) ? wq : (wsel == 1) ? wk : (wsel == 2) ? wv : wo;
    d = (wsel == 0) ? wqb : (wsel == 1) ? wkb : (wsel == 2) ? wvb : wob;
  }
  float4 v = ((const float4*)s)[off];
  uint2 o;
  o.x = (unsigned)f2b(v.x) | ((unsigned)f2b(v.y) << 16);
  o.y = (unsigned)f2b(v.z) | ((unsigned)f2b(v.w) << 16);
  ((uint2*)d)[off] = o;
}

// ---------------- QKV GEMM (m97 pattern): BK=64, global_load_lds staging, XOR-swizzled LDS.
// z in {0,1} (Q,K): computes C^T so each lane holds 4 consecutive hd -> packed 8B stores.
// z == 2   (V):    computes C so each lane holds 4 consecutive s -> packed 8B stores to Vt.
__global__ __launch_bounds__(256, 3) void qkv_gemm(
    const u16* __restrict__ xb, const u16* __restrict__ wq, const u16* __restrict__ wk,
    const u16* __restrict__ wv, u16* __restrict__ Qb, u16* __restrict__ Kb, u16* __restrict__ Vt)
{
  __shared__ __align__(16) u16 As[128 * 64];   // unpadded; chunk c of row r at c^(r&7)
  __shared__ __align__(16) u16 Bs[128 * 64];
  const int t = threadIdx.x;
  const int mblk = blockIdx.x, nblk = blockIdx.y, z = blockIdx.z;
  const u16* W = (z == 0) ? wq : (z == 1) ? wk : wv;
  const int w = t >> 6, lane = t & 63, quad = lane >> 4, l16 = lane & 15;
  const int wr = w >> 1, wc = w & 1;
  const int l7 = l16 & 7;

  f32x4 acc[4][4];
  #pragma unroll
  for (int i = 0; i < 4; i++)
    #pragma unroll
    for (int j = 0; j < 4; j++) acc[i][j] = (f32x4){0.f, 0.f, 0.f, 0.f};

  int srow[4], schk[4];
  #pragma unroll
  for (int i = 0; i < 4; i++) {
    int s = i * 256 + t;
    srow[i] = s >> 3;
    schk[i] = (s & 7) ^ (srow[i] & 7);
  }
  const u16* gA = xb + (size_t)(mblk * 128) * D;
  const u16* gB = W  + (size_t)(nblk * 128) * D;

  for (int k0 = 0; k0 < D; k0 += 64) {
    __syncthreads();   // prior iter's LDS reads done
    #pragma unroll
    for (int i = 0; i < 4; i++) {
      int s = i * 256 + t;
      cp16(gA + (size_t)srow[i] * D + k0 + schk[i] * 8, As + s * 8);
      cp16(gB + (size_t)srow[i] * D + k0 + schk[i] * 8, Bs + s * 8);
    }
    __syncthreads();   // DMA arrived
    #pragma unroll
    for (int j = 0; j < 2; j++) {
      bf16x8 af[4], bfr[4];
      #pragma unroll
      for (int mt = 0; mt < 4; mt++)
        af[mt]  = *(const bf16x8*)(As + (wr * 64 + mt * 16 + l16) * 64 + ((j * 4 + quad) ^ l7) * 8);
      #pragma unroll
      for (int nt = 0; nt < 4; nt++)
        bfr[nt] = *(const bf16x8*)(Bs + (wc * 64 + nt * 16 + l16) * 64 + ((j * 4 + quad) ^ l7) * 8);
      if (z == 2) {
        #pragma unroll
        for (int mt = 0; mt < 4; mt++)
          #pragma unroll
          for (int nt = 0; nt < 4; nt++)
            acc[mt][nt] = MFMA(af[mt], bfr[nt], acc[mt][nt]);
      } else {
        #pragma unroll
        for (int mt = 0; mt < 4; mt++)
          #pragma unroll
          for (int nt = 0; nt < 4; nt++)
            acc[mt][nt] = MFMA(bfr[nt], af[mt], acc[mt][nt]);   // C^T
      }
    }
  }

  const float qscale = 0.18033688011112042f;  // 0.125 * log2(e)
  if (z == 2) {
    #pragma unroll
    for (int mt = 0; mt < 4; mt++) {
      int m0 = mblk * 128 + wr * 64 + mt * 16 + quad * 4;
      int b = m0 >> 12, s0 = m0 & 4095;
      #pragma unroll
      for (int nt = 0; nt < 4; nt++) {
        int n = nblk * 128 + wc * 64 + nt * 16 + l16;
        int h = n >> 6, hd = n & 63;
        u16* p = Vt + (((size_t)(b * H + h) * HD + hd)) * S + s0;  // 4 consecutive s
        uint2 pk;
        pk.x = (unsigned)f2b(acc[mt][nt][0]) | ((unsigned)f2b(acc[mt][nt][1]) << 16);
        pk.y = (unsigned)f2b(acc[mt][nt][2]) | ((unsigned)f2b(acc[mt][nt][3]) << 16);
        *(uint2*)p = pk;
      }
    }
  } else {
    u16* dst = (z == 0) ? Qb : Kb;
    float sc = (z == 0) ? qscale : 1.0f;
    #pragma unroll
    for (int nt = 0; nt < 4; nt++) {
      int n0 = nblk * 128 + wc * 64 + nt * 16 + quad * 4;   // 4 consecutive hd
      int h = n0 >> 6, hd0 = n0 & 63;
      #pragma unroll
      for (int mt = 0; mt < 4; mt++) {
        int m = mblk * 128 + wr * 64 + mt * 16 + l16;       // s
        int b = m >> 12, s = m & 4095;
        uint2 pk;
        pk.x = (unsigned)f2b(acc[mt][nt][0] * sc) | ((unsigned)f2b(acc[mt][nt][1] * sc) << 16);
        pk.y = (unsigned)f2b(acc[mt][nt][2] * sc) | ((unsigned)f2b(acc[mt][nt][3] * sc) << 16);
        *(uint2*)(dst + ((size_t)(b * H + h) * S + s) * HD + hd0) = pk;
      }
    }
  }
}

// ---------------- flash attention (transposed: S^T = K Q^T, O^T = V^T P^T) ----------------
// R9 structure; y->qtile via alternating high/low permutation so the stride-256 co-resident
// sampling gives every CU ~equal total work (fixes the drain-tail imbalance).
__global__ __launch_bounds__(256, 3) void attn(
    const u16* __restrict__ Qb, const u16* __restrict__ Kb,
    const u16* __restrict__ Vt, u16* __restrict__ ctx)
{
  __shared__ __align__(16) u16 Ks[128 * 64];    // K tile [key][hd], chunk c at c^(key&7)   : 16 KB
  __shared__ __align__(16) u16 Vts[64 * 128];   // V^T tile [hd][key], chunk c at c^(hd&15) : 16 KB
  __shared__ __align__(16) u16 Pb[4][32 * 72];  // per-wave P half (64 keys), stride 72     : 18 KB
  const int t = threadIdx.x, w = t >> 6, lane = t & 63, quad = lane >> 4, l16 = lane & 15;
  const int l7 = l16 & 7;
  const int bh = blockIdx.x;
  const int y = (int)blockIdx.y;
  const int qtile = (y & 1) ? ((y - 1) >> 1) : (31 - (y >> 1));  // balanced high/low interleave
  const int q0 = qtile * 128;
  const u16* Qh = Qb + (size_t)bh * S * HD;
  const u16* Kh = Kb + (size_t)bh * S * HD;
  const u16* Vh = Vt + (size_t)bh * S * HD;     // [64][4096]
  u16* Pw = &Pb[w][0];
  const int b = bh / H, h = bh % H;

  bf16x8 qf[2][2];
  #pragma unroll
  for (int rt = 0; rt < 2; rt++)
    #pragma unroll
    for (int ks = 0; ks < 2; ks++)
      qf[rt][ks] = *(const bf16x8*)(Qh + (size_t)(q0 + w * 32 + rt * 16 + l16) * HD + ks * 32 + quad * 8);

  f32x4 ao[2][4];
  #pragma unroll
  for (int rt = 0; rt < 2; rt++)
    #pragma unroll
    for (int co = 0; co < 4; co++) ao[rt][co] = (f32x4){0.f, 0.f, 0.f, 0.f};
  float lsum[2] = {0.f, 0.f};

  int krow[4], kchk[4], vrow[4], vchk[4];
  #pragma unroll
  for (int i = 0; i < 4; i++) {
    int s = i * 256 + t;
    krow[i] = s >> 3;  kchk[i] = (s & 7)  ^ (krow[i] & 7);
    vrow[i] = s >> 4;  vchk[i] = (s & 15) ^ (vrow[i] & 15);
  }

  for (int kv0 = 0; kv0 <= q0; kv0 += 128) {
    const bool diag = (kv0 == q0);
    const int ct_end = diag ? (2 * w + 2) : 8;
    const int ks_end = diag ? (w + 1) : 4;

    __syncthreads();
    #pragma unroll
    for (int i = 0; i < 4; i++) {
      int s = i * 256 + t;
      cp16(Kh + (size_t)(kv0 + krow[i]) * HD + kchk[i] * 8, Ks + s * 8);
      cp16(Vh + (size_t)vrow[i] * S + kv0 + vchk[i] * 8,    Vts + s * 8);
    }
    __syncthreads();

    #pragma unroll
    for (int h2 = 0; h2 < 2; h2++) {
      if (h2 * 4 < ct_end) {
        #pragma unroll
        for (int c2 = 0; c2 < 4; c2++) {
          int ct = h2 * 4 + c2;
          if (ct < ct_end) {
            int krw = ct * 16 + l16;
            bf16x8 kf0 = *(const bf16x8*)(Ks + krw * 64 + ((0 + quad) ^ l7) * 8);
            bf16x8 kf1 = *(const bf16x8*)(Ks + krw * 64 + ((4 + quad) ^ l7) * 8);
            f32x4 s0 = (f32x4){0.f, 0.f, 0.f, 0.f};
            f32x4 s1 = (f32x4){0.f, 0.f, 0.f, 0.f};
            s0 = MFMA(kf0, qf[0][0], s0);  s0 = MFMA(kf1, qf[0][1], s0);
            s1 = MFMA(kf0, qf[1][0], s1);  s1 = MFMA(kf1, qf[1][1], s1);
            if (diag) {
              int keyb = kv0 + ct * 16 + quad * 4;
              int qr0  = q0 + w * 32 + l16;
              #pragma unroll
              for (int r = 0; r < 4; r++) {
                if (keyb + r > qr0)      s0[r] = -1e30f;
                if (keyb + r > qr0 + 16) s1[r] = -1e30f;
              }
            }
            float p0 = __builtin_amdgcn_exp2f(s0[0]);
            float p1 = __builtin_amdgcn_exp2f(s0[1]);
            float p2 = __builtin_amdgcn_exp2f(s0[2]);
            float p3 = __builtin_amdgcn_exp2f(s0[3]);
            lsum[0] += (p0 + p1) + (p2 + p3);
            uint2 pk;
            pk.x = pack_bf16_trunc(p0, p1);
            pk.y = pack_bf16_trunc(p2, p3);
            *(uint2*)(Pw + l16 * 72 + c2 * 16 + quad * 4) = pk;
            p0 = __builtin_amdgcn_exp2f(s1[0]);
            p1 = __builtin_amdgcn_exp2f(s1[1]);
            p2 = __builtin_amdgcn_exp2f(s1[2]);
            p3 = __builtin_amdgcn_exp2f(s1[3]);
            lsum[1] += (p0 + p1) + (p2 + p3);
            pk.x = pack_bf16_trunc(p0, p1);
            pk.y = pack_bf16_trunc(p2, p3);
            *(uint2*)(Pw + (16 + l16) * 72 + c2 * 16 + quad * 4) = pk;
          }
        }
        #pragma unroll
        for (int k2 = 0; k2 < 2; k2++) {
          int ks = h2 * 2 + k2;
          if (ks < ks_end) {
            bf16x8 pf0 = *(const bf16x8*)(Pw + (0  + l16) * 72 + k2 * 32 + quad * 8);
            bf16x8 pf1 = *(const bf16x8*)(Pw + (16 + l16) * 72 + k2 * 32 + quad * 8);
            #pragma unroll
            for (int co = 0; co < 4; co++) {
              int vrw = co * 16 + l16;
              bf16x8 vf = *(const bf16x8*)(Vts + vrw * 128 + ((ks * 4 + quad) ^ (vrw & 15)) * 8);
              ao[0][co] = MFMA(vf, pf0, ao[0][co]);
              ao[1][co] = MFMA(vf, pf1, ao[1][co]);
            }
          }
        }
      }
    }
  }

  #pragma unroll
  for (int rt = 0; rt < 2; rt++) {
    float v = lsum[rt];
    v += __shfl_xor(v, 16, 64);
    v += __shfl_xor(v, 32, 64);
    float inv = 1.0f / v;
    int token = b * S + q0 + w * 32 + rt * 16 + l16;
    #pragma unroll
    for (int co = 0; co < 4; co++) {
      uint2 pk;
      pk.x = (unsigned)f2b(ao[rt][co][0] * inv) | ((unsigned)f2b(ao[rt][co][1] * inv) << 16);
      pk.y = (unsigned)f2b(ao[rt][co][2] * inv) | ((unsigned)f2b(ao[rt][co][3] * inv) << 16);
      *(uint2*)(ctx + (size_t)token * D + h * HD + co * 16 + quad * 4) = pk;
    }
  }
}

// ---------------- output projection (m97 pattern): ctx[8192,768] x Wo^T + bias -> fp32 out
__global__ __launch_bounds__(256, 3) void out_gemm(
    const u16* __restrict__ ctx, const u16* __restrict__ wo,
    const float* __restrict__ bias, float* __restrict__ out)
{
  __shared__ __align__(16) u16 As[128 * 64];
  __shared__ __align__(16) u16 Bs[128 * 64];
  const int t = threadIdx.x;
  const int mblk = blockIdx.x, nblk = blockIdx.y;
  const int w = t >> 6, lane = t & 63, quad = lane >> 4, l16 = lane & 15;
  const int wr = w >> 1, wc = w & 1;
  const int l7 = l16 & 7;

  f32x4 acc[4][4];
  #pragma unroll
  for (int i = 0; i < 4; i++)
    #pragma unroll
    for (int j = 0; j < 4; j++) acc[i][j] = (f32x4){0.f, 0.f, 0.f, 0.f};

  int srow[4], schk[4];
  #pragma unroll
  for (int i = 0; i < 4; i++) {
    int s = i * 256 + t;
    srow[i] = s >> 3;
    schk[i] = (s & 7) ^ (srow[i] & 7);
  }
  const u16* gA = ctx + (size_t)(mblk * 128) * D;
  const u16* gB = wo  + (size_t)(nblk * 128) * D;

  for (int k0 = 0; k0 < D; k0 += 64) {
    __syncthreads();
    #pragma unroll
    for (int i = 0; i < 4; i++) {
      int s = i * 256 + t;
      cp16(gA + (size_t)srow[i] * D + k0 + schk[i] * 8, As + s * 8);
      cp16(gB + (size_t)srow[i] * D + k0 + schk[i] * 8, Bs + s * 8);
    }
    __syncthreads();
    #pragma unroll
    for (int j = 0; j < 2; j++) {
      bf16x8 af[4], bfr[4];
      #pragma unroll
      for (int mt = 0; mt < 4; mt++)
        af[mt]  = *(const bf16x8*)(As + (wr * 64 + mt * 16 + l16) * 64 + ((j * 4 + quad) ^ l7) * 8);
      #pragma unroll
      for (int nt = 0; nt < 4; nt++)
        bfr[nt] = *(const bf16x8*)(Bs + (wc * 64 + nt * 16 + l16) * 64 + ((j * 4 + quad) ^ l7) * 8);
      #pragma unroll
      for (int mt = 0; mt < 4; mt++)
        #pragma unroll
        for (int nt = 0; nt < 4; nt++)
          acc[mt][nt] = MFMA(af[mt], bfr[nt], acc[mt][nt]);
    }
  }

  #pragma unroll
  for (int mt = 0; mt < 4; mt++) {
    int m0 = mblk * 128 + wr * 64 + mt * 16 + quad * 4;
    #pragma unroll
    for (int nt = 0; nt < 4; nt++) {
      int n = nblk * 128 + wc * 64 + nt * 16 + l16;
      float bv = bias[n];
      #pragma unroll
      for (int r = 0; r < 4; r++)
        out[(size_t)(m0 + r) * D + n] = acc[mt][nt][r] + bv;
    }
  }
}

// ---------------- host launch ----------------
extern "C" void kernel_launch(void* const* d_in, const int* in_sizes, int n_in,
                              void* d_out, int out_size, void* d_ws, size_t ws_size,
                              hipStream_t stream) {
  const float* x    = (const float*)d_in[0];
  const float* wq   = (const float*)d_in[1];
  const float* wk   = (const float*)d_in[2];
  const float* wv   = (const float*)d_in[3];
  const float* wo   = (const float*)d_in[4];
  const float* bo   = (const float*)d_in[5];
  float* out = (float*)d_out;

  u16* ws = (u16*)d_ws;
  const size_t NX = (size_t)2 * S * D;      // 6291456
  const size_t NW = (size_t)D * D;          // 589824
  u16* xb  = ws;                // [8192][768]; reused as ctx after qkv_gemm consumes it
  u16* wqb = ws + NX;
  u16* wkb = wqb + NW;
  u16* wvb = wkb + NW;
  u16* wob = wvb + NW;
  u16* Qb  = wob + NW;          // [2][12][4096][64] bf16 (pre-scaled by 0.125*log2e)
  u16* Kb  = Qb + NX;           // bf16
  u16* Vt  = Kb + NX;           // [2][12][64][4096] bf16
  u16* ctx = xb;

  const int total4 = NX4 + 4 * NW4;
  castall<<<(total4 + 255) / 256, 256, 0, stream>>>(x, wq, wk, wv, wo, xb, wqb, wkb, wvb, wob);

  qkv_gemm<<<dim3(64, 6, 3), 256, 0, stream>>>(xb, wqb, wkb, wvb, Qb, Kb, Vt);
  attn<<<dim3(24, 32), 256, 0, stream>>>(Qb, Kb, Vt, ctx);
  out_gemm<<<dim3(64, 6), 256, 0, stream>>>(ctx, wob, bo, out);
}